// Round 6
// baseline (627.190 us; speedup 1.0000x reference)
//
#include <hip/hip_runtime.h>
#include <math.h>

#define B 2
#define L 2048
#define D 1024
#define H 16
#define HD 64
#define W 32
#define M (B * L)          // 4096
#define KP3 3072           // packed K' = 3*D

typedef unsigned short ushort_t;
typedef short bf16x8 __attribute__((ext_vector_type(8)));
typedef float f32x4 __attribute__((ext_vector_type(4)));

static __device__ __forceinline__ unsigned short f2bf(float f) {
    union { float f; unsigned u; } v; v.f = f;
    unsigned r = v.u + 0x7FFF + ((v.u >> 16) & 1);
    return (unsigned short)(r >> 16);
}
static __device__ __forceinline__ float bf2f(unsigned short h) {
    union { unsigned u; float f; } v; v.u = ((unsigned)h) << 16;
    return v.f;
}
static __device__ __forceinline__ unsigned pk2(unsigned a, unsigned b) {
    return a | (b << 16);
}

// ---------------- packing: x -> A-side [hi | lo | hi] ----------------
__global__ __launch_bounds__(256) void pack_x_kernel(
    const float* __restrict__ src, ushort_t* __restrict__ dst)
{
    const int idx = blockIdx.x * 256 + threadIdx.x;
    const int r = idx >> 7;
    const int c = (idx & 127) << 3;
    const float* p = src + (size_t)r * D + c;
    const float4 f0 = *(const float4*)p;
    const float4 f1 = *(const float4*)(p + 4);
    float f[8] = {f0.x, f0.y, f0.z, f0.w, f1.x, f1.y, f1.z, f1.w};
    unsigned short h[8], lo[8];
#pragma unroll
    for (int i = 0; i < 8; ++i) {
        h[i] = f2bf(f[i]);
        lo[i] = f2bf(f[i] - bf2f(h[i]));
    }
    uint4 hv = make_uint4(pk2(h[0], h[1]), pk2(h[2], h[3]), pk2(h[4], h[5]), pk2(h[6], h[7]));
    uint4 lv = make_uint4(pk2(lo[0], lo[1]), pk2(lo[2], lo[3]), pk2(lo[4], lo[5]), pk2(lo[6], lo[7]));
    ushort_t* d = dst + (size_t)r * KP3 + c;
    *(uint4*)(d)         = hv;
    *(uint4*)(d + D)     = lv;
    *(uint4*)(d + 2 * D) = hv;
}

// ---------------- packing: weights -> B-side [hi | hi | lo] ----------------
__global__ __launch_bounds__(256) void pack_w_kernel(
    const float* __restrict__ s0, const float* __restrict__ s1,
    const float* __restrict__ s2, ushort_t* __restrict__ dst, int nrows)
{
    const int idx = blockIdx.x * 256 + threadIdx.x;
    const int r = idx >> 7;
    if (r >= nrows) return;
    const int c = (idx & 127) << 3;
    const float* src = (r < 1024) ? s0 : ((r < 2048) ? s1 : s2);
    const float* p = src + (size_t)(r & 1023) * D + c;
    const float4 f0 = *(const float4*)p;
    const float4 f1 = *(const float4*)(p + 4);
    float f[8] = {f0.x, f0.y, f0.z, f0.w, f1.x, f1.y, f1.z, f1.w};
    unsigned short h[8], lo[8];
#pragma unroll
    for (int i = 0; i < 8; ++i) {
        h[i] = f2bf(f[i]);
        lo[i] = f2bf(f[i] - bf2f(h[i]));
    }
    uint4 hv = make_uint4(pk2(h[0], h[1]), pk2(h[2], h[3]), pk2(h[4], h[5]), pk2(h[6], h[7]));
    uint4 lv = make_uint4(pk2(lo[0], lo[1]), pk2(lo[2], lo[3]), pk2(lo[4], lo[5]), pk2(lo[6], lo[7]));
    ushort_t* d = dst + (size_t)r * KP3 + c;
    *(uint4*)(d)         = hv;
    *(uint4*)(d + D)     = hv;
    *(uint4*)(d + 2 * D) = lv;
}

// ---------------- conn kernel (tiny) ----------------
__global__ __launch_bounds__(512) void conn_kernel(
    const float* __restrict__ cw1, const float* __restrict__ cw2,
    const float* __restrict__ cw3, float* __restrict__ conn)
{
    __shared__ float vals[H][W];
    const int t = threadIdx.x;
    const int h = t >> 5;
    const int w = t & 31;
    const float pos = (float)w / (float)(W - 1);
    float s = 0.f;
    for (int k = 0; k < 128; ++k) {
        const float a1 = pos * cw1[h * 128 + k];
        const float a3 = pos * cw3[h * 128 + k];
        const float si = a1 / (1.f + expf(-a1));
        s += si * a3 * cw2[h * 128 + k];
    }
    vals[h][w] = s;
    __syncthreads();
    float mx = -1e30f;
    for (int i = 0; i < W; ++i) mx = fmaxf(mx, vals[h][i]);
    float den = 0.f;
    for (int i = 0; i < W; ++i) den += expf(vals[h][i] - mx);
    conn[t] = expf(s - mx) / den;
}

// ---------------- 256x256 8-phase split-bf16 MFMA GEMM ----------------
// C[M,N] = A'[*,3072-slice] * B'[*,3072-slice]^T
// 8 waves (2M x 4N), per-wave 128x64 C-tile, BK=64, dbuf halves in 128KB LDS.
// mode 1: QKV (RoPE on Q/K, scatter);  mode 2: partial fp32 (split-K via blockIdx.z)

#define SBAR() __builtin_amdgcn_s_barrier()
#define WAIT_LGKM0() { asm volatile("s_waitcnt lgkmcnt(0)" ::: "memory"); __builtin_amdgcn_sched_barrier(0); }
#define WAIT_VM(n)   { asm volatile("s_waitcnt vmcnt(" #n ")" ::: "memory"); __builtin_amdgcn_sched_barrier(0); }
#define PRIO1() __builtin_amdgcn_s_setprio(1)
#define PRIO0() __builtin_amdgcn_s_setprio(0)

#define STAGE_A(hh, tt, dd) do { \
    __builtin_amdgcn_global_load_lds((const __attribute__((address_space(1))) void*)(pA##hh##0 + (size_t)(tt) * 64), \
        (__attribute__((address_space(3))) void*)(lds + (dd) * 32768 + (hh) * 8192 + (w * 16 + 0) * 64), 16, 0, 0); \
    __builtin_amdgcn_global_load_lds((const __attribute__((address_space(1))) void*)(pA##hh##1 + (size_t)(tt) * 64), \
        (__attribute__((address_space(3))) void*)(lds + (dd) * 32768 + (hh) * 8192 + (w * 16 + 8) * 64), 16, 0, 0); \
} while (0)

#define STAGE_B(hh, tt, dd) do { \
    __builtin_amdgcn_global_load_lds((const __attribute__((address_space(1))) void*)(pB##hh##0 + (size_t)(tt) * 64), \
        (__attribute__((address_space(3))) void*)(lds + (dd) * 32768 + 16384 + (hh) * 8192 + (w * 16 + 0) * 64), 16, 0, 0); \
    __builtin_amdgcn_global_load_lds((const __attribute__((address_space(1))) void*)(pB##hh##1 + (size_t)(tt) * 64), \
        (__attribute__((address_space(3))) void*)(lds + (dd) * 32768 + 16384 + (hh) * 8192 + (w * 16 + 8) * 64), 16, 0, 0); \
} while (0)

#define READ_A(qm, dd) do { \
    _Pragma("unroll") for (int mi = 0; mi < 4; ++mi) { \
        a[mi][0] = *(const bf16x8*)(lds + (dd) * 32768 + (qm) * 8192 + (baseA + mi * 16) * 64 + ch0); \
        a[mi][1] = *(const bf16x8*)(lds + (dd) * 32768 + (qm) * 8192 + (baseA + mi * 16) * 64 + ch1); } \
} while (0)

#define READ_B(qn, dd, bb) do { \
    _Pragma("unroll") for (int ni = 0; ni < 2; ++ni) { \
        bb[ni][0] = *(const bf16x8*)(lds + (dd) * 32768 + 16384 + (qn) * 8192 + (baseB + ni * 16) * 64 + ch0); \
        bb[ni][1] = *(const bf16x8*)(lds + (dd) * 32768 + 16384 + (qn) * 8192 + (baseB + ni * 16) * 64 + ch1); } \
} while (0)

#define MMA(qm, qn, bb) do { \
    _Pragma("unroll") for (int mi = 0; mi < 4; ++mi) \
    _Pragma("unroll") for (int ni = 0; ni < 2; ++ni) { \
        acc[(qm)*4+mi][(qn)*2+ni] = __builtin_amdgcn_mfma_f32_16x16x32_bf16(a[mi][0], bb[ni][0], acc[(qm)*4+mi][(qn)*2+ni], 0, 0, 0); \
        acc[(qm)*4+mi][(qn)*2+ni] = __builtin_amdgcn_mfma_f32_16x16x32_bf16(a[mi][1], bb[ni][1], acc[(qm)*4+mi][(qn)*2+ni], 0, 0, 0); } \
} while (0)

__global__ __launch_bounds__(512, 2) void gemm8(
    const ushort_t* __restrict__ Ap, const ushort_t* __restrict__ Bp,
    int nkt, int mode, float* __restrict__ outp,
    float* __restrict__ qb, float* __restrict__ kb, float* __restrict__ vb,
    const float* __restrict__ rc, const float* __restrict__ rs)
{
    extern __shared__ short lds[];    // 128 KiB: [d][A h0,A h1,B h0,B h1], half = 128x64 bf16
    const int tid = threadIdx.x;
    const int w = tid >> 6;           // wave 0..7
    const int ln = tid & 63;
    const int wr = w >> 2, wc = w & 3;
    const int n0 = blockIdx.x * 256;
    const int m0 = blockIdx.y * 256;
    const int z = blockIdx.z;

    if (mode == 2) { Ap += (size_t)z * 1536; Bp += (size_t)z * 1536; }

    // ---- staging source pointers (pre-swizzled chunk: logical = (ln&7)^(ln>>3)) ----
    const int lchk = ((ln & 7) ^ (ln >> 3)) * 8;
    const ushort_t *pA00, *pA01, *pA10, *pA11, *pB00, *pB01, *pB10, *pB11;
    {
        const int r0 = w * 16 + (ln >> 3);          // q=0
        const int r1 = w * 16 + 8 + (ln >> 3);      // q=1
#define GROWA(rl, hh) (m0 + ((rl) & 63) + (((rl) >> 6) * 128) + (hh) * 64)
#define GROWB(rl, hh) (n0 + ((rl) & 31) + (((rl) >> 5) * 64) + (hh) * 32)
        pA00 = Ap + (size_t)GROWA(r0, 0) * KP3 + lchk;
        pA01 = Ap + (size_t)GROWA(r1, 0) * KP3 + lchk;
        pA10 = Ap + (size_t)GROWA(r0, 1) * KP3 + lchk;
        pA11 = Ap + (size_t)GROWA(r1, 1) * KP3 + lchk;
        pB00 = Bp + (size_t)GROWB(r0, 0) * KP3 + lchk;
        pB01 = Bp + (size_t)GROWB(r1, 0) * KP3 + lchk;
        pB10 = Bp + (size_t)GROWB(r0, 1) * KP3 + lchk;
        pB11 = Bp + (size_t)GROWB(r1, 1) * KP3 + lchk;
    }

    // ---- read-side bases ----
    const int baseA = wr * 64 + (ln & 15);
    const int baseB = wc * 32 + (ln & 15);
    const int ch0 = ((0 * 4 + (ln >> 4)) ^ (ln & 7)) * 8;   // kk=0 chunk (shorts)
    const int ch1 = ((1 * 4 + (ln >> 4)) ^ (ln & 7)) * 8;   // kk=1

    f32x4 acc[8][4];
#pragma unroll
    for (int i = 0; i < 8; ++i)
#pragma unroll
        for (int j = 0; j < 4; ++j) acc[i][j] = (f32x4){0.f, 0.f, 0.f, 0.f};

    bf16x8 a[4][2], b0[2][2], b1[2][2];

    // ---- prologue: Ah0(0) Bh0(0) Bh1(0) Ah1(0) Ah0(1) Bh0(1) ----
    STAGE_A(0, 0, 0); STAGE_B(0, 0, 0); STAGE_B(1, 0, 0); STAGE_A(1, 0, 0);
    STAGE_A(0, 1, 1); STAGE_B(0, 1, 1);
    WAIT_VM(8);
    SBAR();

    const int niters = nkt >> 1;
    for (int it = 0; it < niters; ++it) {
        const int t1 = 2 * it + 1;
        const int t2 = (2 * it + 2 < nkt) ? 2 * it + 2 : 0;   // clamped (keeps vmcnt math exact)
        const int t3 = (2 * it + 3 < nkt) ? 2 * it + 3 : 1;
        // ph1: tile t0 (buf0) quad (0,0)
        READ_A(0, 0); READ_B(0, 0, b0); STAGE_A(1, t1, 1);
        SBAR(); WAIT_LGKM0(); PRIO1(); MMA(0, 0, b0); PRIO0(); WAIT_VM(6); SBAR();
        // ph2: quad (0,1)
        READ_B(1, 0, b1); STAGE_B(1, t1, 1);
        SBAR(); WAIT_LGKM0(); PRIO1(); MMA(0, 1, b1); PRIO0(); SBAR();
        // ph3: quad (1,0)
        READ_A(1, 0); STAGE_A(0, t2, 0);
        SBAR(); WAIT_LGKM0(); PRIO1(); MMA(1, 0, b0); PRIO0(); SBAR();
        // ph4: quad (1,1)
        STAGE_B(0, t2, 0);
        SBAR(); PRIO1(); MMA(1, 1, b1); PRIO0(); WAIT_VM(8); SBAR();
        // ph5: tile t1 (buf1) quad (0,0)
        READ_A(0, 1); READ_B(0, 1, b0); STAGE_A(1, t2, 0);
        SBAR(); WAIT_LGKM0(); PRIO1(); MMA(0, 0, b0); PRIO0(); WAIT_VM(6); SBAR();
        // ph6: quad (0,1)
        READ_B(1, 1, b1); STAGE_B(1, t2, 0);
        SBAR(); WAIT_LGKM0(); PRIO1(); MMA(0, 1, b1); PRIO0(); SBAR();
        // ph7: quad (1,0)
        READ_A(1, 1); STAGE_A(0, t3, 1);
        SBAR(); WAIT_LGKM0(); PRIO1(); MMA(1, 0, b0); PRIO0(); SBAR();
        // ph8: quad (1,1)
        STAGE_B(0, t3, 1);
        SBAR(); PRIO1(); MMA(1, 1, b1); PRIO0(); WAIT_VM(8); SBAR();
    }

    // ---- epilogue: C/D layout col = ln&15, row = (ln>>4)*4 + j ----
    if (mode == 1) {
#pragma unroll
        for (int mf = 0; mf < 8; ++mf)
#pragma unroll
            for (int nf = 0; nf < 4; ++nf)
#pragma unroll
                for (int j = 0; j < 4; ++j) {
                    const int m = m0 + wr * 128 + mf * 16 + (ln >> 4) * 4 + j;
                    const int n = n0 + wc * 64 + nf * 16 + (ln & 15);
                    const int which = n >> 10;
                    float* dst = (which == 0) ? qb : ((which == 1) ? kb : vb);
                    const int bb = m >> 11;
                    const int l = m & (L - 1);
                    const int nn = n & 1023;
                    const int hh = nn >> 6;
                    const int hd = nn & 63;
                    float v = acc[mf][nf][j];
                    if (which < 2) {
                        const int ip = hd >> 1;
                        const float c = rc[l * (HD / 2) + ip];
                        const float s = rs[l * (HD / 2) + ip];
                        const float p = __shfl_xor(v, 1);
                        v = (hd & 1) ? fmaf(p, s, v * c) : fmaf(p, -s, v * c);
                    }
                    dst[(((size_t)(bb * H + hh)) * L + l) * HD + hd] = v;
                }
    } else {
        float* dst = outp + (size_t)z * ((size_t)M * 1024);
#pragma unroll
        for (int mf = 0; mf < 8; ++mf)
#pragma unroll
            for (int nf = 0; nf < 4; ++nf)
#pragma unroll
                for (int j = 0; j < 4; ++j) {
                    const int m = m0 + wr * 128 + mf * 16 + (ln >> 4) * 4 + j;
                    const int n = n0 + wc * 64 + nf * 16 + (ln & 15);
                    dst[(size_t)m * 1024 + n] = acc[mf][nf][j];
                }
    }
}

// ---------------- split-K reduce ----------------
__global__ __launch_bounds__(256) void reduce_kernel(
    const float* __restrict__ p, float* __restrict__ out)
{
    const size_t i = ((size_t)blockIdx.x * 256 + threadIdx.x) * 4;
    const float4 a = *(const float4*)(p + i);
    const float4 b = *(const float4*)(p + (size_t)M * 1024 + i);
    *(float4*)(out + i) = make_float4(a.x + b.x, a.y + b.y, a.z + b.z, a.w + b.w);
}

// ---------------- sliding-window attention (K->V LDS reuse) ----------------
#define QT 64
#define KR (QT + W - 1)    // 95
#define KPAD 68

__global__ __launch_bounds__(64) void attn_kernel(
    const float* __restrict__ qb, const float* __restrict__ kb,
    const float* __restrict__ vb, const float* __restrict__ conn,
    ushort_t* __restrict__ aop)
{
    __shared__ float Ks[KR][KPAD];   // 25.8 KB -> 6 blocks/CU
    const int tid = threadIdx.x;
    const int l0 = blockIdx.x * QT;
    const int bh = blockIdx.y;
    const int h = bh & (H - 1);
    const int bb = bh >> 4;
    const float* Qg = qb + (size_t)bh * L * HD;
    const float* Kg = kb + (size_t)bh * L * HD;
    const float* Vg = vb + (size_t)bh * L * HD;

    const int l = l0 + tid;
    float4 q[16];
#pragma unroll
    for (int i = 0; i < 16; ++i) q[i] = *(const float4*)(Qg + (size_t)l * HD + i * 4);

    // stage K rows [l0-31 .. l0+63]; out-of-range -> zeros (reference zero-pad)
    for (int idx = tid; idx < KR * 16; idx += 64) {
        const int rr = idx >> 4;
        const int f4 = (idx & 15) << 2;
        const int lr = l0 - (W - 1) + rr;
        float4 kv = make_float4(0, 0, 0, 0);
        if (lr >= 0) kv = *(const float4*)(Kg + (size_t)lr * HD + f4);
        *(float4*)&Ks[rr][f4] = kv;
    }
    __syncthreads();

    float sc[W];
#pragma unroll
    for (int w = 0; w < W; ++w) {
        const float* kr = Ks[tid + w];
        float s = 0.f;
#pragma unroll
        for (int i = 0; i < 16; ++i) {
            const float4 kv = *(const float4*)(kr + i * 4);
            s = fmaf(q[i].x, kv.x, s);
            s = fmaf(q[i].y, kv.y, s);
            s = fmaf(q[i].z, kv.z, s);
            s = fmaf(q[i].w, kv.w, s);
        }
        sc[w] = s * 0.125f;
    }

    float mx = -1e30f;
#pragma unroll
    for (int w = 0; w < W; ++w) mx = fmaxf(mx, sc[w]);
    float den = 0.f;
#pragma unroll
    for (int w = 0; w < W; ++w) { sc[w] = expf(sc[w] - mx); den += sc[w]; }
    const float inv = 1.f / den;
    float fsum = 0.f;
#pragma unroll
    for (int w = 0; w < W; ++w) {
        sc[w] = sc[w] * inv * conn[h * W + w];
        fsum += sc[w];
    }
    const float rn = 1.f / (fsum + 1e-9f);

    __syncthreads();   // all lanes done reading K before overwrite
    // stage V into the same buffer
    for (int idx = tid; idx < KR * 16; idx += 64) {
        const int rr = idx >> 4;
        const int f4 = (idx & 15) << 2;
        const int lr = l0 - (W - 1) + rr;
        float4 vv = make_float4(0, 0, 0, 0);
        if (lr >= 0) vv = *(const float4*)(Vg + (size_t)lr * HD + f4);
        *(float4*)&Ks[rr][f4] = vv;
    }
    __syncthreads();

    float4 o[16];
#pragma unroll
    for (int i = 0; i < 16; ++i) o[i] = make_float4(0, 0, 0, 0);
#pragma unroll
    for (int w = 0; w < W; ++w) {
        const float wt = sc[w] * rn;
        const float* vr = Ks[tid + w];
#pragma unroll
        for (int i = 0; i < 16; ++i) {
            const float4 vv = *(const float4*)(vr + i * 4);
            o[i].x = fmaf(wt, vv.x, o[i].x);
            o[i].y = fmaf(wt, vv.y, o[i].y);
            o[i].z = fmaf(wt, vv.z, o[i].z);
            o[i].w = fmaf(wt, vv.w, o[i].w);
        }
    }

    // write packed A-side rows [hi | lo | hi] for the out-projection GEMM
    const int m = bb * L + l;
    ushort_t* dp = aop + (size_t)m * KP3 + h * HD;
#pragma unroll
    for (int i = 0; i < 16; ++i) {
        float f[4] = {o[i].x, o[i].y, o[i].z, o[i].w};
        unsigned short hh[4], lo[4];
#pragma unroll
        for (int j = 0; j < 4; ++j) {
            hh[j] = f2bf(f[j]);
            lo[j] = f2bf(f[j] - bf2f(hh[j]));
        }
        uint2 hv = make_uint2(pk2(hh[0], hh[1]), pk2(hh[2], hh[3]));
        uint2 lv = make_uint2(pk2(lo[0], lo[1]), pk2(lo[2], lo[3]));
        *(uint2*)(dp + i * 4)         = hv;
        *(uint2*)(dp + D + i * 4)     = lv;
        *(uint2*)(dp + 2 * D + i * 4) = hv;
    }
}

// ---------------- launcher ----------------
extern "C" void kernel_launch(void* const* d_in, const int* in_sizes, int n_in,
                              void* d_out, int out_size, void* d_ws, size_t ws_size,
                              hipStream_t stream)
{
    const float* x   = (const float*)d_in[0];
    const float* wq  = (const float*)d_in[1];
    const float* wk  = (const float*)d_in[2];
    const float* wv  = (const float*)d_in[3];
    const float* wo  = (const float*)d_in[4];
    const float* cw1 = (const float*)d_in[5];
    const float* cw2 = (const float*)d_in[6];
    const float* cw3 = (const float*)d_in[7];
    const float* rc  = (const float*)d_in[8];
    const float* rs  = (const float*)d_in[9];
    float* out = (float*)d_out;

    float* ws = (float*)d_ws;
    float* conn = ws;                                  // 1024 floats
    float* qb = ws + 1024;                             // [B*H][L][HD] fp32
    float* kb = qb + (size_t)B * H * L * HD;
    float* vb = kb + (size_t)B * H * L * HD;
    ushort_t* xp    = (ushort_t*)(vb + (size_t)B * H * L * HD);  // [M][3072] bf16 (reused as attn out)
    ushort_t* wqkvp = xp + (size_t)M * KP3;            // [3072][3072] bf16
    ushort_t* wop   = wqkvp + (size_t)3072 * KP3;      // [1024][3072] bf16
    float* part = qb;                                  // reuse qb/kb region for split-K partials (33.6MB < 48MB)

    hipFuncSetAttribute((const void*)gemm8, hipFuncAttributeMaxDynamicSharedMemorySize, 131072);

    pack_x_kernel<<<dim3(M * 128 / 256), dim3(256), 0, stream>>>(x, xp);
    pack_w_kernel<<<dim3(3072 * 128 / 256), dim3(256), 0, stream>>>(wq, wk, wv, wqkvp, 3072);
    pack_w_kernel<<<dim3(1024 * 128 / 256), dim3(256), 0, stream>>>(wo, wo, wo, wop, 1024);
    conn_kernel<<<dim3(1), dim3(512), 0, stream>>>(cw1, cw2, cw3, conn);

    gemm8<<<dim3(12, 16, 1), dim3(512), 131072, stream>>>(
        xp, wqkvp, 48, 1, nullptr, qb, kb, vb, rc, rs);

    attn_kernel<<<dim3(L / QT, B * H), dim3(64), 0, stream>>>(qb, kb, vb, conn, xp);

    gemm8<<<dim3(4, 16, 2), dim3(512), 131072, stream>>>(
        xp, wop, 24, 2, part, nullptr, nullptr, nullptr, rc, rs);

    reduce_kernel<<<dim3(M * 1024 / 1024), dim3(256), 0, stream>>>(part, out);
}

// Round 7
// 339.637 us; speedup vs baseline: 1.8467x; 1.8467x over previous
//
#include <hip/hip_runtime.h>
#include <math.h>

#define B 2
#define L 2048
#define D 1024
#define H 16
#define HD 64
#define W 32
#define M (B * L)          // 4096
#define KP3 3072           // packed K' = 3*D

typedef unsigned short ushort_t;
typedef short bf16x8 __attribute__((ext_vector_type(8)));
typedef float f32x4 __attribute__((ext_vector_type(4)));

static __device__ __forceinline__ unsigned short f2bf(float f) {
    union { float f; unsigned u; } v; v.f = f;
    unsigned r = v.u + 0x7FFF + ((v.u >> 16) & 1);
    return (unsigned short)(r >> 16);
}
static __device__ __forceinline__ float bf2f(unsigned short h) {
    union { unsigned u; float f; } v; v.u = ((unsigned)h) << 16;
    return v.f;
}
static __device__ __forceinline__ unsigned pk2(unsigned a, unsigned b) {
    return a | (b << 16);
}

// ---------------- packing: fp32 [r][1024] -> A-side [hi | lo | hi] ----------------
// (used for both x->xp and attn-out ao->xp)
__global__ __launch_bounds__(256) void pack_x_kernel(
    const float* __restrict__ src, ushort_t* __restrict__ dst)
{
    const int idx = blockIdx.x * 256 + threadIdx.x;
    const int r = idx >> 7;
    const int c = (idx & 127) << 3;
    const float* p = src + (size_t)r * D + c;
    const float4 f0 = *(const float4*)p;
    const float4 f1 = *(const float4*)(p + 4);
    float f[8] = {f0.x, f0.y, f0.z, f0.w, f1.x, f1.y, f1.z, f1.w};
    unsigned short h[8], lo[8];
#pragma unroll
    for (int i = 0; i < 8; ++i) {
        h[i] = f2bf(f[i]);
        lo[i] = f2bf(f[i] - bf2f(h[i]));
    }
    uint4 hv = make_uint4(pk2(h[0], h[1]), pk2(h[2], h[3]), pk2(h[4], h[5]), pk2(h[6], h[7]));
    uint4 lv = make_uint4(pk2(lo[0], lo[1]), pk2(lo[2], lo[3]), pk2(lo[4], lo[5]), pk2(lo[6], lo[7]));
    ushort_t* d = dst + (size_t)r * KP3 + c;
    *(uint4*)(d)         = hv;
    *(uint4*)(d + D)     = lv;
    *(uint4*)(d + 2 * D) = hv;
}

// ---------------- packing: weights -> B-side [hi | hi | lo] ----------------
__global__ __launch_bounds__(256) void pack_w_kernel(
    const float* __restrict__ s0, const float* __restrict__ s1,
    const float* __restrict__ s2, ushort_t* __restrict__ dst, int nrows)
{
    const int idx = blockIdx.x * 256 + threadIdx.x;
    const int r = idx >> 7;
    if (r >= nrows) return;
    const int c = (idx & 127) << 3;
    const float* src = (r < 1024) ? s0 : ((r < 2048) ? s1 : s2);
    const float* p = src + (size_t)(r & 1023) * D + c;
    const float4 f0 = *(const float4*)p;
    const float4 f1 = *(const float4*)(p + 4);
    float f[8] = {f0.x, f0.y, f0.z, f0.w, f1.x, f1.y, f1.z, f1.w};
    unsigned short h[8], lo[8];
#pragma unroll
    for (int i = 0; i < 8; ++i) {
        h[i] = f2bf(f[i]);
        lo[i] = f2bf(f[i] - bf2f(h[i]));
    }
    uint4 hv = make_uint4(pk2(h[0], h[1]), pk2(h[2], h[3]), pk2(h[4], h[5]), pk2(h[6], h[7]));
    uint4 lv = make_uint4(pk2(lo[0], lo[1]), pk2(lo[2], lo[3]), pk2(lo[4], lo[5]), pk2(lo[6], lo[7]));
    ushort_t* d = dst + (size_t)r * KP3 + c;
    *(uint4*)(d)         = hv;
    *(uint4*)(d + D)     = hv;
    *(uint4*)(d + 2 * D) = lv;
}

// ---------------- conn kernel (tiny) ----------------
__global__ __launch_bounds__(512) void conn_kernel(
    const float* __restrict__ cw1, const float* __restrict__ cw2,
    const float* __restrict__ cw3, float* __restrict__ conn)
{
    __shared__ float vals[H][W];
    const int t = threadIdx.x;
    const int h = t >> 5;
    const int w = t & 31;
    const float pos = (float)w / (float)(W - 1);
    float s = 0.f;
    for (int k = 0; k < 128; ++k) {
        const float a1 = pos * cw1[h * 128 + k];
        const float a3 = pos * cw3[h * 128 + k];
        const float si = a1 / (1.f + expf(-a1));
        s += si * a3 * cw2[h * 128 + k];
    }
    vals[h][w] = s;
    __syncthreads();
    float mx = -1e30f;
    for (int i = 0; i < W; ++i) mx = fmaxf(mx, vals[h][i]);
    float den = 0.f;
    for (int i = 0; i < W; ++i) den += expf(vals[h][i] - mx);
    conn[t] = expf(s - mx) / den;
}

// ---------------- 256x256 8-phase split-bf16 MFMA GEMM ----------------
// (unchanged from round 3 — next round gets its counters)

#define SBAR() __builtin_amdgcn_s_barrier()
#define WAIT_LGKM0() { asm volatile("s_waitcnt lgkmcnt(0)" ::: "memory"); __builtin_amdgcn_sched_barrier(0); }
#define WAIT_VM(n)   { asm volatile("s_waitcnt vmcnt(" #n ")" ::: "memory"); __builtin_amdgcn_sched_barrier(0); }
#define PRIO1() __builtin_amdgcn_s_setprio(1)
#define PRIO0() __builtin_amdgcn_s_setprio(0)

#define STAGE_A(hh, tt, dd) do { \
    __builtin_amdgcn_global_load_lds((const __attribute__((address_space(1))) void*)(pA##hh##0 + (size_t)(tt) * 64), \
        (__attribute__((address_space(3))) void*)(lds + (dd) * 32768 + (hh) * 8192 + (w * 16 + 0) * 64), 16, 0, 0); \
    __builtin_amdgcn_global_load_lds((const __attribute__((address_space(1))) void*)(pA##hh##1 + (size_t)(tt) * 64), \
        (__attribute__((address_space(3))) void*)(lds + (dd) * 32768 + (hh) * 8192 + (w * 16 + 8) * 64), 16, 0, 0); \
} while (0)

#define STAGE_B(hh, tt, dd) do { \
    __builtin_amdgcn_global_load_lds((const __attribute__((address_space(1))) void*)(pB##hh##0 + (size_t)(tt) * 64), \
        (__attribute__((address_space(3))) void*)(lds + (dd) * 32768 + 16384 + (hh) * 8192 + (w * 16 + 0) * 64), 16, 0, 0); \
    __builtin_amdgcn_global_load_lds((const __attribute__((address_space(1))) void*)(pB##hh##1 + (size_t)(tt) * 64), \
        (__attribute__((address_space(3))) void*)(lds + (dd) * 32768 + 16384 + (hh) * 8192 + (w * 16 + 8) * 64), 16, 0, 0); \
} while (0)

#define READ_A(qm, dd) do { \
    _Pragma("unroll") for (int mi = 0; mi < 4; ++mi) { \
        a[mi][0] = *(const bf16x8*)(lds + (dd) * 32768 + (qm) * 8192 + (baseA + mi * 16) * 64 + ch0); \
        a[mi][1] = *(const bf16x8*)(lds + (dd) * 32768 + (qm) * 8192 + (baseA + mi * 16) * 64 + ch1); } \
} while (0)

#define READ_B(qn, dd, bb) do { \
    _Pragma("unroll") for (int ni = 0; ni < 2; ++ni) { \
        bb[ni][0] = *(const bf16x8*)(lds + (dd) * 32768 + 16384 + (qn) * 8192 + (baseB + ni * 16) * 64 + ch0); \
        bb[ni][1] = *(const bf16x8*)(lds + (dd) * 32768 + 16384 + (qn) * 8192 + (baseB + ni * 16) * 64 + ch1); } \
} while (0)

#define MMA(qm, qn, bb) do { \
    _Pragma("unroll") for (int mi = 0; mi < 4; ++mi) \
    _Pragma("unroll") for (int ni = 0; ni < 2; ++ni) { \
        acc[(qm)*4+mi][(qn)*2+ni] = __builtin_amdgcn_mfma_f32_16x16x32_bf16(a[mi][0], bb[ni][0], acc[(qm)*4+mi][(qn)*2+ni], 0, 0, 0); \
        acc[(qm)*4+mi][(qn)*2+ni] = __builtin_amdgcn_mfma_f32_16x16x32_bf16(a[mi][1], bb[ni][1], acc[(qm)*4+mi][(qn)*2+ni], 0, 0, 0); } \
} while (0)

__global__ __launch_bounds__(512, 2) void gemm8(
    const ushort_t* __restrict__ Ap, const ushort_t* __restrict__ Bp,
    int nkt, int mode, float* __restrict__ outp,
    float* __restrict__ qb, float* __restrict__ kb, float* __restrict__ vb,
    const float* __restrict__ rc, const float* __restrict__ rs)
{
    extern __shared__ short lds[];
    const int tid = threadIdx.x;
    const int w = tid >> 6;
    const int ln = tid & 63;
    const int wr = w >> 2, wc = w & 3;
    const int n0 = blockIdx.x * 256;
    const int m0 = blockIdx.y * 256;
    const int z = blockIdx.z;

    if (mode == 2) { Ap += (size_t)z * 1536; Bp += (size_t)z * 1536; }

    const int lchk = ((ln & 7) ^ (ln >> 3)) * 8;
    const ushort_t *pA00, *pA01, *pA10, *pA11, *pB00, *pB01, *pB10, *pB11;
    {
        const int r0 = w * 16 + (ln >> 3);
        const int r1 = w * 16 + 8 + (ln >> 3);
#define GROWA(rl, hh) (m0 + ((rl) & 63) + (((rl) >> 6) * 128) + (hh) * 64)
#define GROWB(rl, hh) (n0 + ((rl) & 31) + (((rl) >> 5) * 64) + (hh) * 32)
        pA00 = Ap + (size_t)GROWA(r0, 0) * KP3 + lchk;
        pA01 = Ap + (size_t)GROWA(r1, 0) * KP3 + lchk;
        pA10 = Ap + (size_t)GROWA(r0, 1) * KP3 + lchk;
        pA11 = Ap + (size_t)GROWA(r1, 1) * KP3 + lchk;
        pB00 = Bp + (size_t)GROWB(r0, 0) * KP3 + lchk;
        pB01 = Bp + (size_t)GROWB(r1, 0) * KP3 + lchk;
        pB10 = Bp + (size_t)GROWB(r0, 1) * KP3 + lchk;
        pB11 = Bp + (size_t)GROWB(r1, 1) * KP3 + lchk;
    }

    const int baseA = wr * 64 + (ln & 15);
    const int baseB = wc * 32 + (ln & 15);
    const int ch0 = ((0 * 4 + (ln >> 4)) ^ (ln & 7)) * 8;
    const int ch1 = ((1 * 4 + (ln >> 4)) ^ (ln & 7)) * 8;

    f32x4 acc[8][4];
#pragma unroll
    for (int i = 0; i < 8; ++i)
#pragma unroll
        for (int j = 0; j < 4; ++j) acc[i][j] = (f32x4){0.f, 0.f, 0.f, 0.f};

    bf16x8 a[4][2], b0[2][2], b1[2][2];

    STAGE_A(0, 0, 0); STAGE_B(0, 0, 0); STAGE_B(1, 0, 0); STAGE_A(1, 0, 0);
    STAGE_A(0, 1, 1); STAGE_B(0, 1, 1);
    WAIT_VM(8);
    SBAR();

    const int niters = nkt >> 1;
    for (int it = 0; it < niters; ++it) {
        const int t1 = 2 * it + 1;
        const int t2 = (2 * it + 2 < nkt) ? 2 * it + 2 : 0;
        const int t3 = (2 * it + 3 < nkt) ? 2 * it + 3 : 1;
        READ_A(0, 0); READ_B(0, 0, b0); STAGE_A(1, t1, 1);
        SBAR(); WAIT_LGKM0(); PRIO1(); MMA(0, 0, b0); PRIO0(); WAIT_VM(6); SBAR();
        READ_B(1, 0, b1); STAGE_B(1, t1, 1);
        SBAR(); WAIT_LGKM0(); PRIO1(); MMA(0, 1, b1); PRIO0(); SBAR();
        READ_A(1, 0); STAGE_A(0, t2, 0);
        SBAR(); WAIT_LGKM0(); PRIO1(); MMA(1, 0, b0); PRIO0(); SBAR();
        STAGE_B(0, t2, 0);
        SBAR(); PRIO1(); MMA(1, 1, b1); PRIO0(); WAIT_VM(8); SBAR();
        READ_A(0, 1); READ_B(0, 1, b0); STAGE_A(1, t2, 0);
        SBAR(); WAIT_LGKM0(); PRIO1(); MMA(0, 0, b0); PRIO0(); WAIT_VM(6); SBAR();
        READ_B(1, 1, b1); STAGE_B(1, t2, 0);
        SBAR(); WAIT_LGKM0(); PRIO1(); MMA(0, 1, b1); PRIO0(); SBAR();
        READ_A(1, 1); STAGE_A(0, t3, 1);
        SBAR(); WAIT_LGKM0(); PRIO1(); MMA(1, 0, b0); PRIO0(); SBAR();
        STAGE_B(0, t3, 1);
        SBAR(); PRIO1(); MMA(1, 1, b1); PRIO0(); WAIT_VM(8); SBAR();
    }

    if (mode == 1) {
#pragma unroll
        for (int mf = 0; mf < 8; ++mf)
#pragma unroll
            for (int nf = 0; nf < 4; ++nf)
#pragma unroll
                for (int j = 0; j < 4; ++j) {
                    const int m = m0 + wr * 128 + mf * 16 + (ln >> 4) * 4 + j;
                    const int n = n0 + wc * 64 + nf * 16 + (ln & 15);
                    const int which = n >> 10;
                    float* dst = (which == 0) ? qb : ((which == 1) ? kb : vb);
                    const int bb = m >> 11;
                    const int l = m & (L - 1);
                    const int nn = n & 1023;
                    const int hh = nn >> 6;
                    const int hd = nn & 63;
                    float v = acc[mf][nf][j];
                    if (which < 2) {
                        const int ip = hd >> 1;
                        const float c = rc[l * (HD / 2) + ip];
                        const float s = rs[l * (HD / 2) + ip];
                        const float p = __shfl_xor(v, 1);
                        v = (hd & 1) ? fmaf(p, s, v * c) : fmaf(p, -s, v * c);
                    }
                    dst[(((size_t)(bb * H + hh)) * L + l) * HD + hd] = v;
                }
    } else {
        float* dst = outp + (size_t)z * ((size_t)M * 1024);
#pragma unroll
        for (int mf = 0; mf < 8; ++mf)
#pragma unroll
            for (int nf = 0; nf < 4; ++nf)
#pragma unroll
                for (int j = 0; j < 4; ++j) {
                    const int m = m0 + wr * 128 + mf * 16 + (ln >> 4) * 4 + j;
                    const int n = n0 + wc * 64 + nf * 16 + (ln & 15);
                    dst[(size_t)m * 1024 + n] = acc[mf][nf][j];
                }
    }
}

// ---------------- split-K reduce ----------------
__global__ __launch_bounds__(256) void reduce_kernel(
    const float* __restrict__ p, float* __restrict__ out)
{
    const size_t i = ((size_t)blockIdx.x * 256 + threadIdx.x) * 4;
    const float4 a = *(const float4*)(p + i);
    const float4 b = *(const float4*)(p + (size_t)M * 1024 + i);
    *(float4*)(out + i) = make_float4(a.x + b.x, a.y + b.y, a.z + b.z, a.w + b.w);
}

// ---------------- sliding-window attention (coalesced f32 output) ----------------
#define QT 64
#define KR (QT + W - 1)    // 95
#define KPAD 68

__global__ __launch_bounds__(64) void attn_kernel(
    const float* __restrict__ qb, const float* __restrict__ kb,
    const float* __restrict__ vb, const float* __restrict__ conn,
    float* __restrict__ ao)
{
    __shared__ float Ks[KR][KPAD];
    __shared__ float Vs[KR][KPAD];   // 51.7 KB -> 3 blocks/CU
    const int tid = threadIdx.x;
    const int l0 = blockIdx.x * QT;
    const int bh = blockIdx.y;
    const int h = bh & (H - 1);
    const int bb = bh >> 4;
    const float* Qg = qb + (size_t)bh * L * HD;
    const float* Kg = kb + (size_t)bh * L * HD;
    const float* Vg = vb + (size_t)bh * L * HD;

    const int l = l0 + tid;
    float4 q[16];
#pragma unroll
    for (int i = 0; i < 16; ++i) q[i] = *(const float4*)(Qg + (size_t)l * HD + i * 4);

    // stage K and V rows [l0-31 .. l0+63] together (loads overlap);
    // out-of-range rows are zeros (reference zero-pad: score 0, INCLUDED in softmax)
    for (int idx = tid; idx < KR * 16; idx += 64) {
        const int rr = idx >> 4;
        const int f4 = (idx & 15) << 2;
        const int lr = l0 - (W - 1) + rr;
        float4 kv = make_float4(0, 0, 0, 0);
        float4 vv = make_float4(0, 0, 0, 0);
        if (lr >= 0) {
            kv = *(const float4*)(Kg + (size_t)lr * HD + f4);
            vv = *(const float4*)(Vg + (size_t)lr * HD + f4);
        }
        *(float4*)&Ks[rr][f4] = kv;
        *(float4*)&Vs[rr][f4] = vv;
    }
    __syncthreads();

    float sc[W];
#pragma unroll
    for (int w = 0; w < W; ++w) {
        const float* kr = Ks[tid + w];
        float s = 0.f;
#pragma unroll
        for (int i = 0; i < 16; ++i) {
            const float4 kv = *(const float4*)(kr + i * 4);
            s = fmaf(q[i].x, kv.x, s);
            s = fmaf(q[i].y, kv.y, s);
            s = fmaf(q[i].z, kv.z, s);
            s = fmaf(q[i].w, kv.w, s);
        }
        sc[w] = s * 0.125f;
    }

    float mx = -1e30f;
#pragma unroll
    for (int w = 0; w < W; ++w) mx = fmaxf(mx, sc[w]);
    float den = 0.f;
#pragma unroll
    for (int w = 0; w < W; ++w) { sc[w] = expf(sc[w] - mx); den += sc[w]; }
    const float inv = 1.f / den;
    float fsum = 0.f;
#pragma unroll
    for (int w = 0; w < W; ++w) {
        sc[w] = sc[w] * inv * conn[h * W + w];
        fsum += sc[w];
    }
    const float rn = 1.f / (fsum + 1e-9f);

    float4 o[16];
#pragma unroll
    for (int i = 0; i < 16; ++i) o[i] = make_float4(0, 0, 0, 0);
#pragma unroll
    for (int w = 0; w < W; ++w) {
        const float wt = sc[w] * rn;
        const float* vr = Vs[tid + w];
#pragma unroll
        for (int i = 0; i < 16; ++i) {
            const float4 vv = *(const float4*)(vr + i * 4);
            o[i].x = fmaf(wt, vv.x, o[i].x);
            o[i].y = fmaf(wt, vv.y, o[i].y);
            o[i].z = fmaf(wt, vv.z, o[i].z);
            o[i].w = fmaf(wt, vv.w, o[i].w);
        }
    }

    // coalesced f32 store: thread writes 256B contiguous (4 full cache lines)
    float* dst = ao + ((size_t)(bb * L + l) * D + h * HD);
#pragma unroll
    for (int i = 0; i < 16; ++i) *(float4*)(dst + i * 4) = o[i];
}

// ---------------- launcher ----------------
extern "C" void kernel_launch(void* const* d_in, const int* in_sizes, int n_in,
                              void* d_out, int out_size, void* d_ws, size_t ws_size,
                              hipStream_t stream)
{
    const float* x   = (const float*)d_in[0];
    const float* wq  = (const float*)d_in[1];
    const float* wk  = (const float*)d_in[2];
    const float* wv  = (const float*)d_in[3];
    const float* wo  = (const float*)d_in[4];
    const float* cw1 = (const float*)d_in[5];
    const float* cw2 = (const float*)d_in[6];
    const float* cw3 = (const float*)d_in[7];
    const float* rc  = (const float*)d_in[8];
    const float* rs  = (const float*)d_in[9];
    float* out = (float*)d_out;

    float* ws = (float*)d_ws;
    float* conn = ws;                                  // 1024 floats
    float* qb = ws + 1024;                             // [B*H][L][HD] fp32
    float* kb = qb + (size_t)B * H * L * HD;
    float* vb = kb + (size_t)B * H * L * HD;
    ushort_t* xp    = (ushort_t*)(vb + (size_t)B * H * L * HD);  // [M][3072] bf16
    ushort_t* wqkvp = xp + (size_t)M * KP3;            // [3072][3072] bf16
    ushort_t* wop   = wqkvp + (size_t)3072 * KP3;      // [1024][3072] bf16
    float* part = qb;                                  // split-K partials (reuse qb/kb)
    float* ao = (float*)wqkvp;                         // attn f32 out [M][1024] (wqkvp dead after QKV gemm; 16.8MB < 18.9MB)

    hipFuncSetAttribute((const void*)gemm8, hipFuncAttributeMaxDynamicSharedMemorySize, 131072);

    pack_x_kernel<<<dim3(M * 128 / 256), dim3(256), 0, stream>>>(x, xp);
    pack_w_kernel<<<dim3(3072 * 128 / 256), dim3(256), 0, stream>>>(wq, wk, wv, wqkvp, 3072);
    pack_w_kernel<<<dim3(1024 * 128 / 256), dim3(256), 0, stream>>>(wo, wo, wo, wop, 1024);
    conn_kernel<<<dim3(1), dim3(512), 0, stream>>>(cw1, cw2, cw3, conn);

    gemm8<<<dim3(12, 16, 1), dim3(512), 131072, stream>>>(
        xp, wqkvp, 48, 1, nullptr, qb, kb, vb, rc, rs);

    attn_kernel<<<dim3(L / QT, B * H), dim3(64), 0, stream>>>(qb, kb, vb, conn, ao);

    // repack attn output (fp32, coalesced) into split-bf16 A-side rows
    pack_x_kernel<<<dim3(M * 128 / 256), dim3(256), 0, stream>>>(ao, xp);

    gemm8<<<dim3(4, 16, 2), dim3(512), 131072, stream>>>(
        xp, wop, 24, 2, part, nullptr, nullptr, nullptr, rc, rs);

    reduce_kernel<<<dim3(M * 1024 / 1024), dim3(256), 0, stream>>>(part, out);
}

// Round 9
// 307.390 us; speedup vs baseline: 2.0404x; 1.1049x over previous
//
#include <hip/hip_runtime.h>
#include <math.h>

#define B 2
#define L 2048
#define D 1024
#define H 16
#define HD 64
#define W 32
#define M (B * L)          // 4096
#define KP3 3072           // packed K' = 3*D

typedef unsigned short ushort_t;
typedef short bf16x8 __attribute__((ext_vector_type(8)));
typedef float f32x4 __attribute__((ext_vector_type(4)));

static __device__ __forceinline__ unsigned short f2bf(float f) {
    union { float f; unsigned u; } v; v.f = f;
    unsigned r = v.u + 0x7FFF + ((v.u >> 16) & 1);
    return (unsigned short)(r >> 16);
}
static __device__ __forceinline__ float bf2f(unsigned short h) {
    union { unsigned u; float f; } v; v.u = ((unsigned)h) << 16;
    return v.f;
}
static __device__ __forceinline__ unsigned pk2(unsigned a, unsigned b) {
    return a | (b << 16);
}

// ---------------- packing: fp32 [r][1024] -> A-side [hi | lo | hi] ----------------
__global__ __launch_bounds__(256) void pack_x_kernel(
    const float* __restrict__ src, ushort_t* __restrict__ dst)
{
    const int idx = blockIdx.x * 256 + threadIdx.x;
    const int r = idx >> 7;
    const int c = (idx & 127) << 3;
    const float* p = src + (size_t)r * D + c;
    const float4 f0 = *(const float4*)p;
    const float4 f1 = *(const float4*)(p + 4);
    float f[8] = {f0.x, f0.y, f0.z, f0.w, f1.x, f1.y, f1.z, f1.w};
    unsigned short h[8], lo[8];
#pragma unroll
    for (int i = 0; i < 8; ++i) {
        h[i] = f2bf(f[i]);
        lo[i] = f2bf(f[i] - bf2f(h[i]));
    }
    uint4 hv = make_uint4(pk2(h[0], h[1]), pk2(h[2], h[3]), pk2(h[4], h[5]), pk2(h[6], h[7]));
    uint4 lv = make_uint4(pk2(lo[0], lo[1]), pk2(lo[2], lo[3]), pk2(lo[4], lo[5]), pk2(lo[6], lo[7]));
    ushort_t* d = dst + (size_t)r * KP3 + c;
    *(uint4*)(d)         = hv;
    *(uint4*)(d + D)     = lv;
    *(uint4*)(d + 2 * D) = hv;
}

// ---------------- packing: weights -> B-side [hi | hi | lo] ----------------
__global__ __launch_bounds__(256) void pack_w_kernel(
    const float* __restrict__ s0, const float* __restrict__ s1,
    const float* __restrict__ s2, ushort_t* __restrict__ dst, int nrows)
{
    const int idx = blockIdx.x * 256 + threadIdx.x;
    const int r = idx >> 7;
    if (r >= nrows) return;
    const int c = (idx & 127) << 3;
    const float* src = (r < 1024) ? s0 : ((r < 2048) ? s1 : s2);
    const float* p = src + (size_t)(r & 1023) * D + c;
    const float4 f0 = *(const float4*)p;
    const float4 f1 = *(const float4*)(p + 4);
    float f[8] = {f0.x, f0.y, f0.z, f0.w, f1.x, f1.y, f1.z, f1.w};
    unsigned short h[8], lo[8];
#pragma unroll
    for (int i = 0; i < 8; ++i) {
        h[i] = f2bf(f[i]);
        lo[i] = f2bf(f[i] - bf2f(h[i]));
    }
    uint4 hv = make_uint4(pk2(h[0], h[1]), pk2(h[2], h[3]), pk2(h[4], h[5]), pk2(h[6], h[7]));
    uint4 lv = make_uint4(pk2(lo[0], lo[1]), pk2(lo[2], lo[3]), pk2(lo[4], lo[5]), pk2(lo[6], lo[7]));
    ushort_t* d = dst + (size_t)r * KP3 + c;
    *(uint4*)(d)         = hv;
    *(uint4*)(d + D)     = hv;
    *(uint4*)(d + 2 * D) = lv;
}

// ---------------- conn kernel (tiny) ----------------
__global__ __launch_bounds__(512) void conn_kernel(
    const float* __restrict__ cw1, const float* __restrict__ cw2,
    const float* __restrict__ cw3, float* __restrict__ conn)
{
    __shared__ float vals[H][W];
    const int t = threadIdx.x;
    const int h = t >> 5;
    const int w = t & 31;
    const float pos = (float)w / (float)(W - 1);
    float s = 0.f;
    for (int k = 0; k < 128; ++k) {
        const float a1 = pos * cw1[h * 128 + k];
        const float a3 = pos * cw3[h * 128 + k];
        const float si = a1 / (1.f + expf(-a1));
        s += si * a3 * cw2[h * 128 + k];
    }
    vals[h][w] = s;
    __syncthreads();
    float mx = -1e30f;
    for (int i = 0; i < W; ++i) mx = fmaxf(mx, vals[h][i]);
    float den = 0.f;
    for (int i = 0; i < W; ++i) den += expf(vals[h][i] - mx);
    conn[t] = expf(s - mx) / den;
}

// ---------------- 256x256 8-phase split-bf16 MFMA GEMM (+XCD swizzle) ----------------

#define SBAR() __builtin_amdgcn_s_barrier()
#define WAIT_LGKM0() { asm volatile("s_waitcnt lgkmcnt(0)" ::: "memory"); __builtin_amdgcn_sched_barrier(0); }
#define WAIT_VM(n)   { asm volatile("s_waitcnt vmcnt(" #n ")" ::: "memory"); __builtin_amdgcn_sched_barrier(0); }
#define PRIO1() __builtin_amdgcn_s_setprio(1)
#define PRIO0() __builtin_amdgcn_s_setprio(0)

#define STAGE_A(hh, tt, dd) do { \
    __builtin_amdgcn_global_load_lds((const __attribute__((address_space(1))) void*)(pA##hh##0 + (size_t)(tt) * 64), \
        (__attribute__((address_space(3))) void*)(lds + (dd) * 32768 + (hh) * 8192 + (w * 16 + 0) * 64), 16, 0, 0); \
    __builtin_amdgcn_global_load_lds((const __attribute__((address_space(1))) void*)(pA##hh##1 + (size_t)(tt) * 64), \
        (__attribute__((address_space(3))) void*)(lds + (dd) * 32768 + (hh) * 8192 + (w * 16 + 8) * 64), 16, 0, 0); \
} while (0)

#define STAGE_B(hh, tt, dd) do { \
    __builtin_amdgcn_global_load_lds((const __attribute__((address_space(1))) void*)(pB##hh##0 + (size_t)(tt) * 64), \
        (__attribute__((address_space(3))) void*)(lds + (dd) * 32768 + 16384 + (hh) * 8192 + (w * 16 + 0) * 64), 16, 0, 0); \
    __builtin_amdgcn_global_load_lds((const __attribute__((address_space(1))) void*)(pB##hh##1 + (size_t)(tt) * 64), \
        (__attribute__((address_space(3))) void*)(lds + (dd) * 32768 + 16384 + (hh) * 8192 + (w * 16 + 8) * 64), 16, 0, 0); \
} while (0)

#define READ_A(qm, dd) do { \
    _Pragma("unroll") for (int mi = 0; mi < 4; ++mi) { \
        a[mi][0] = *(const bf16x8*)(lds + (dd) * 32768 + (qm) * 8192 + (baseA + mi * 16) * 64 + ch0); \
        a[mi][1] = *(const bf16x8*)(lds + (dd) * 32768 + (qm) * 8192 + (baseA + mi * 16) * 64 + ch1); } \
} while (0)

#define READ_B(qn, dd, bb) do { \
    _Pragma("unroll") for (int ni = 0; ni < 2; ++ni) { \
        bb[ni][0] = *(const bf16x8*)(lds + (dd) * 32768 + 16384 + (qn) * 8192 + (baseB + ni * 16) * 64 + ch0); \
        bb[ni][1] = *(const bf16x8*)(lds + (dd) * 32768 + 16384 + (qn) * 8192 + (baseB + ni * 16) * 64 + ch1); } \
} while (0)

#define MMA(qm, qn, bb) do { \
    _Pragma("unroll") for (int mi = 0; mi < 4; ++mi) \
    _Pragma("unroll") for (int ni = 0; ni < 2; ++ni) { \
        acc[(qm)*4+mi][(qn)*2+ni] = __builtin_amdgcn_mfma_f32_16x16x32_bf16(a[mi][0], bb[ni][0], acc[(qm)*4+mi][(qn)*2+ni], 0, 0, 0); \
        acc[(qm)*4+mi][(qn)*2+ni] = __builtin_amdgcn_mfma_f32_16x16x32_bf16(a[mi][1], bb[ni][1], acc[(qm)*4+mi][(qn)*2+ni], 0, 0, 0); } \
} while (0)

__global__ __launch_bounds__(512, 2) void gemm8(
    const ushort_t* __restrict__ Ap, const ushort_t* __restrict__ Bp,
    int nkt, int mode, float* __restrict__ outp,
    float* __restrict__ qb, float* __restrict__ kb, float* __restrict__ vb,
    const float* __restrict__ rc, const float* __restrict__ rs)
{
    extern __shared__ short lds[];
    const int tid = threadIdx.x;
    const int w = tid >> 6;
    const int ln = tid & 63;
    const int wr = w >> 2, wc = w & 3;

    // XCD-aware bijective swizzle (nwg % 8 == 0 for both call sites)
    const int gx = gridDim.x;
    const int nwg = gx * gridDim.y;
    int fid = blockIdx.y * gx + blockIdx.x;
    fid = (fid & 7) * (nwg >> 3) + (fid >> 3);
    const int n0 = (fid % gx) * 256;
    const int m0 = (fid / gx) * 256;
    const int z = blockIdx.z;

    if (mode == 2) { Ap += (size_t)z * 1536; Bp += (size_t)z * 1536; }

    const int lchk = ((ln & 7) ^ (ln >> 3)) * 8;
    const ushort_t *pA00, *pA01, *pA10, *pA11, *pB00, *pB01, *pB10, *pB11;
    {
        const int r0 = w * 16 + (ln >> 3);
        const int r1 = w * 16 + 8 + (ln >> 3);
#define GROWA(rl, hh) (m0 + ((rl) & 63) + (((rl) >> 6) * 128) + (hh) * 64)
#define GROWB(rl, hh) (n0 + ((rl) & 31) + (((rl) >> 5) * 64) + (hh) * 32)
        pA00 = Ap + (size_t)GROWA(r0, 0) * KP3 + lchk;
        pA01 = Ap + (size_t)GROWA(r1, 0) * KP3 + lchk;
        pA10 = Ap + (size_t)GROWA(r0, 1) * KP3 + lchk;
        pA11 = Ap + (size_t)GROWA(r1, 1) * KP3 + lchk;
        pB00 = Bp + (size_t)GROWB(r0, 0) * KP3 + lchk;
        pB01 = Bp + (size_t)GROWB(r1, 0) * KP3 + lchk;
        pB10 = Bp + (size_t)GROWB(r0, 1) * KP3 + lchk;
        pB11 = Bp + (size_t)GROWB(r1, 1) * KP3 + lchk;
    }

    const int baseA = wr * 64 + (ln & 15);
    const int baseB = wc * 32 + (ln & 15);
    const int ch0 = ((0 * 4 + (ln >> 4)) ^ (ln & 7)) * 8;
    const int ch1 = ((1 * 4 + (ln >> 4)) ^ (ln & 7)) * 8;

    f32x4 acc[8][4];
#pragma unroll
    for (int i = 0; i < 8; ++i)
#pragma unroll
        for (int j = 0; j < 4; ++j) acc[i][j] = (f32x4){0.f, 0.f, 0.f, 0.f};

    bf16x8 a[4][2], b0[2][2], b1[2][2];

    STAGE_A(0, 0, 0); STAGE_B(0, 0, 0); STAGE_B(1, 0, 0); STAGE_A(1, 0, 0);
    STAGE_A(0, 1, 1); STAGE_B(0, 1, 1);
    WAIT_VM(8);
    SBAR();

    const int niters = nkt >> 1;
    for (int it = 0; it < niters; ++it) {
        const int t1 = 2 * it + 1;
        const int t2 = (2 * it + 2 < nkt) ? 2 * it + 2 : 0;
        const int t3 = (2 * it + 3 < nkt) ? 2 * it + 3 : 1;
        READ_A(0, 0); READ_B(0, 0, b0); STAGE_A(1, t1, 1);
        SBAR(); WAIT_LGKM0(); PRIO1(); MMA(0, 0, b0); PRIO0(); WAIT_VM(6); SBAR();
        READ_B(1, 0, b1); STAGE_B(1, t1, 1);
        SBAR(); WAIT_LGKM0(); PRIO1(); MMA(0, 1, b1); PRIO0(); SBAR();
        READ_A(1, 0); STAGE_A(0, t2, 0);
        SBAR(); WAIT_LGKM0(); PRIO1(); MMA(1, 0, b0); PRIO0(); SBAR();
        STAGE_B(0, t2, 0);
        SBAR(); PRIO1(); MMA(1, 1, b1); PRIO0(); WAIT_VM(8); SBAR();
        READ_A(0, 1); READ_B(0, 1, b0); STAGE_A(1, t2, 0);
        SBAR(); WAIT_LGKM0(); PRIO1(); MMA(0, 0, b0); PRIO0(); WAIT_VM(6); SBAR();
        READ_B(1, 1, b1); STAGE_B(1, t2, 0);
        SBAR(); WAIT_LGKM0(); PRIO1(); MMA(0, 1, b1); PRIO0(); SBAR();
        READ_A(1, 1); STAGE_A(0, t3, 1);
        SBAR(); WAIT_LGKM0(); PRIO1(); MMA(1, 0, b0); PRIO0(); SBAR();
        STAGE_B(0, t3, 1);
        SBAR(); PRIO1(); MMA(1, 1, b1); PRIO0(); WAIT_VM(8); SBAR();
    }

    if (mode == 1) {
#pragma unroll
        for (int mf = 0; mf < 8; ++mf)
#pragma unroll
            for (int nf = 0; nf < 4; ++nf)
#pragma unroll
                for (int j = 0; j < 4; ++j) {
                    const int m = m0 + wr * 128 + mf * 16 + (ln >> 4) * 4 + j;
                    const int n = n0 + wc * 64 + nf * 16 + (ln & 15);
                    const int which = n >> 10;
                    float* dst = (which == 0) ? qb : ((which == 1) ? kb : vb);
                    const int bb = m >> 11;
                    const int l = m & (L - 1);
                    const int nn = n & 1023;
                    const int hh = nn >> 6;
                    const int hd = nn & 63;
                    float v = acc[mf][nf][j];
                    if (which < 2) {
                        const int ip = hd >> 1;
                        const float c = rc[l * (HD / 2) + ip];
                        const float s = rs[l * (HD / 2) + ip];
                        const float p = __shfl_xor(v, 1);
                        v = (hd & 1) ? fmaf(p, s, v * c) : fmaf(p, -s, v * c);
                    }
                    dst[(((size_t)(bb * H + hh)) * L + l) * HD + hd] = v;
                }
    } else {
        float* dst = outp + (size_t)z * ((size_t)M * 1024);
#pragma unroll
        for (int mf = 0; mf < 8; ++mf)
#pragma unroll
            for (int nf = 0; nf < 4; ++nf)
#pragma unroll
                for (int j = 0; j < 4; ++j) {
                    const int m = m0 + wr * 128 + mf * 16 + (ln >> 4) * 4 + j;
                    const int n = n0 + wc * 64 + nf * 16 + (ln & 15);
                    dst[(size_t)m * 1024 + n] = acc[mf][nf][j];
                }
    }
}

// ---------------- split-K reduce ----------------
__global__ __launch_bounds__(256) void reduce_kernel(
    const float* __restrict__ p, float* __restrict__ out)
{
    const size_t i = ((size_t)blockIdx.x * 256 + threadIdx.x) * 4;
    const float4 a = *(const float4*)(p + i);
    const float4 b = *(const float4*)(p + (size_t)M * 1024 + i);
    *(float4*)(out + i) = make_float4(a.x + b.x, a.y + b.y, a.z + b.z, a.w + b.w);
}

// ---------------- sliding-window attention (4 waves, 4 lanes per q-row) ----------------
#define QT 64
#define KR (QT + W - 1)    // 95
#define KPAD 68

__global__ __launch_bounds__(256) void attn_kernel(
    const float* __restrict__ qb, const float* __restrict__ kb,
    const float* __restrict__ vb, const float* __restrict__ conn,
    float* __restrict__ ao)
{
    __shared__ float Ks[KR][KPAD];
    __shared__ float Vs[KR][KPAD];   // 51.7 KB -> 3 blocks/CU = 12 waves/CU
    const int tid = threadIdx.x;
    const int r = tid >> 2;          // q-row within tile (0..63)
    const int p = tid & 3;           // hd quarter (16 floats each)
    const int l0 = blockIdx.x * QT;
    const int bh = blockIdx.y;
    const int h = bh & (H - 1);
    const int bb = bh >> 4;
    const float* Qg = qb + (size_t)bh * L * HD;
    const float* Kg = kb + (size_t)bh * L * HD;
    const float* Vg = vb + (size_t)bh * L * HD;

    // stage K/V rows [l0-31 .. l0+63]; out-of-range rows are zeros (reference
    // zero-pad: score exactly 0, INCLUDED in softmax)
    for (int idx = tid; idx < KR * 16; idx += 256) {
        const int rr = idx >> 4;
        const int f4 = (idx & 15) << 2;
        const int lr = l0 - (W - 1) + rr;
        float4 kv = make_float4(0, 0, 0, 0);
        float4 vv = make_float4(0, 0, 0, 0);
        if (lr >= 0) {
            kv = *(const float4*)(Kg + (size_t)lr * HD + f4);
            vv = *(const float4*)(Vg + (size_t)lr * HD + f4);
        }
        *(float4*)&Ks[rr][f4] = kv;
        *(float4*)&Vs[rr][f4] = vv;
    }

    const int l = l0 + r;
    float4 q[4];
#pragma unroll
    for (int i = 0; i < 4; ++i)
        q[i] = *(const float4*)(Qg + (size_t)l * HD + p * 16 + i * 4);

    __syncthreads();

    float sc[W];
#pragma unroll
    for (int w = 0; w < W; ++w) {
        const float* kr = &Ks[r + w][p * 16];
        float s = 0.f;
#pragma unroll
        for (int i = 0; i < 4; ++i) {
            const float4 kv = *(const float4*)(kr + i * 4);
            s = fmaf(q[i].x, kv.x, s);
            s = fmaf(q[i].y, kv.y, s);
            s = fmaf(q[i].z, kv.z, s);
            s = fmaf(q[i].w, kv.w, s);
        }
        // 4-lane partial-dot reduce; all 4 lanes end with the full dot
        s += __shfl_xor(s, 1);
        s += __shfl_xor(s, 2);
        sc[w] = s * 0.125f;
    }

    // softmax + conn (redundant in the 4 lanes of a row; identical values)
    float mx = -1e30f;
#pragma unroll
    for (int w = 0; w < W; ++w) mx = fmaxf(mx, sc[w]);
    float den = 0.f;
#pragma unroll
    for (int w = 0; w < W; ++w) { sc[w] = expf(sc[w] - mx); den += sc[w]; }
    const float inv = 1.f / den;
    float fsum = 0.f;
#pragma unroll
    for (int w = 0; w < W; ++w) {
        sc[w] = sc[w] * inv * conn[h * W + w];
        fsum += sc[w];
    }
    const float rn = 1.f / (fsum + 1e-9f);

    float4 o[4];
#pragma unroll
    for (int i = 0; i < 4; ++i) o[i] = make_float4(0, 0, 0, 0);
#pragma unroll
    for (int w = 0; w < W; ++w) {
        const float wt = sc[w] * rn;
        const float* vr = &Vs[r + w][p * 16];
#pragma unroll
        for (int i = 0; i < 4; ++i) {
            const float4 vv = *(const float4*)(vr + i * 4);
            o[i].x = fmaf(wt, vv.x, o[i].x);
            o[i].y = fmaf(wt, vv.y, o[i].y);
            o[i].z = fmaf(wt, vv.z, o[i].z);
            o[i].w = fmaf(wt, vv.w, o[i].w);
        }
    }

    // coalesced: each lane stores 64B contiguous; 4-lane group = 256B line-aligned
    float* dst = ao + ((size_t)(bb * L + l) * D + h * HD + p * 16);
#pragma unroll
    for (int i = 0; i < 4; ++i) *(float4*)(dst + i * 4) = o[i];
}

// ---------------- launcher ----------------
extern "C" void kernel_launch(void* const* d_in, const int* in_sizes, int n_in,
                              void* d_out, int out_size, void* d_ws, size_t ws_size,
                              hipStream_t stream)
{
    const float* x   = (const float*)d_in[0];
    const float* wq  = (const float*)d_in[1];
    const float* wk  = (const float*)d_in[2];
    const float* wv  = (const float*)d_in[3];
    const float* wo  = (const float*)d_in[4];
    const float* cw1 = (const float*)d_in[5];
    const float* cw2 = (const float*)d_in[6];
    const float* cw3 = (const float*)d_in[7];
    const float* rc  = (const float*)d_in[8];
    const float* rs  = (const float*)d_in[9];
    float* out = (float*)d_out;

    float* ws = (float*)d_ws;
    float* conn = ws;                                  // 1024 floats
    float* qb = ws + 1024;                             // [B*H][L][HD] fp32
    float* kb = qb + (size_t)B * H * L * HD;
    float* vb = kb + (size_t)B * H * L * HD;
    ushort_t* xp    = (ushort_t*)(vb + (size_t)B * H * L * HD);  // [M][3072] bf16
    ushort_t* wqkvp = xp + (size_t)M * KP3;            // [3072][3072] bf16
    ushort_t* wop   = wqkvp + (size_t)3072 * KP3;      // [1024][3072] bf16
    float* part = qb;                                  // split-K partials (reuse qb/kb)
    float* ao = (float*)wqkvp;                         // attn f32 out [M][1024] (wqkvp dead after QKV gemm)

    hipFuncSetAttribute((const void*)gemm8, hipFuncAttributeMaxDynamicSharedMemorySize, 131072);

    pack_x_kernel<<<dim3(M * 128 / 256), dim3(256), 0, stream>>>(x, xp);
    pack_w_kernel<<<dim3(3072 * 128 / 256), dim3(256), 0, stream>>>(wq, wk, wv, wqkvp, 3072);
    pack_w_kernel<<<dim3(1024 * 128 / 256), dim3(256), 0, stream>>>(wo, wo, wo, wop, 1024);
    conn_kernel<<<dim3(1), dim3(512), 0, stream>>>(cw1, cw2, cw3, conn);

    gemm8<<<dim3(12, 16, 1), dim3(512), 131072, stream>>>(
        xp, wqkvp, 48, 1, nullptr, qb, kb, vb, rc, rs);

    attn_kernel<<<dim3(L / QT, B * H), dim3(256), 0, stream>>>(qb, kb, vb, conn, ao);

    // repack attn output (fp32, coalesced) into split-bf16 A-side rows
    pack_x_kernel<<<dim3(M * 128 / 256), dim3(256), 0, stream>>>(ao, xp);

    gemm8<<<dim3(4, 16, 2), dim3(512), 131072, stream>>>(
        xp, wop, 24, 2, part, nullptr, nullptr, nullptr, rc, rs);

    reduce_kernel<<<dim3(M * 1024 / 1024), dim3(256), 0, stream>>>(part, out);
}